// Round 7
// baseline (326.531 us; speedup 1.0000x reference)
//
#include <hip/hip_runtime.h>
#include <cstdint>

#define B_TOK 8192
#define DIM   512
#define NEXP  8
#define HID   2048

#define BM 128
#define BN 128
#define BK 64
#define BN2 64                           // gemm2 n-tile
#define MAXTILES (B_TOK * 2 / BM + NEXP) // 136 padded m-tiles max
#define PAD_SLOTS (MAXTILES * BM)        // 17408

typedef float  floatx4 __attribute__((ext_vector_type(4)));
typedef __bf16 bf16x8  __attribute__((ext_vector_type(8)));

__device__ __forceinline__ unsigned short f2bf(float f){
  unsigned u = __float_as_uint(f);
  u += 0x7fffu + ((u >> 16) & 1u);
  return (unsigned short)(u >> 16);
}

__device__ __forceinline__ float bf2f(unsigned short u){
  return __uint_as_float((unsigned)u << 16);
}

// Abramowitz-Stegun 7.1.26 erf: max abs err 1.5e-7, straight-line (~15 VALU ops)
// vs libm erff's branchy ~30+. R4: erff epilogue made VALUBusy 39% > MfmaUtil 12%.
__device__ __forceinline__ float erf_fast(float x){
  float ax = fabsf(x);
  float t  = 1.0f / (1.0f + 0.3275911f * ax);
  float p  = t * (0.254829592f + t * (-0.284496736f + t * (1.421413741f +
             t * (-1.453152027f + t * 1.061405429f))));
  float r  = 1.0f - p * __expf(-ax * ax);
  return copysignf(r, x);
}

__device__ __forceinline__ float gelu_fast(float v){
  return 0.5f * v * (1.0f + erf_fast(v * 0.70710678118654752440f));
}

// global -> LDS async, 16B per lane. LDS dest is wave-uniform base + lane*16.
__device__ __forceinline__ void async_load16(const void* g, void* l){
  __builtin_amdgcn_global_load_lds(
      (__attribute__((address_space(1))) unsigned int*)const_cast<void*>(g),
      (__attribute__((address_space(3))) unsigned int*)l, 16, 0, 0);
}

// ---------------- prep kernels ----------------

__global__ void k_cvt_x(const float* __restrict__ x, unsigned short* __restrict__ xb){
  int i = blockIdx.x * blockDim.x + threadIdx.x;
  float4 v = ((const float4*)x)[i];
  ushort4 o;
  o.x = f2bf(v.x); o.y = f2bf(v.y); o.z = f2bf(v.z); o.w = f2bf(v.w);
  ((ushort4*)xb)[i] = o;
}

// transpose per-expert [R][C] fp32 -> [C][R] bf16
__global__ __launch_bounds__(256)
void k_transpose_bf16(const float* __restrict__ src, unsigned short* __restrict__ dst,
                      int R, int C){
  __shared__ unsigned short tile[64][65];
  const size_t eoff = (size_t)blockIdx.z * (size_t)R * (size_t)C;
  const float* s = src + eoff;
  unsigned short* d = dst + eoff;
  int r0 = blockIdx.y * 64, c0 = blockIdx.x * 64;
  int tr = threadIdx.x >> 4, tc = threadIdx.x & 15;
  #pragma unroll
  for (int i = 0; i < 4; i++){
    int r = tr + i * 16;
    float4 v = *(const float4*)(s + (size_t)(r0 + r) * C + c0 + tc * 4);
    tile[tc*4+0][r] = f2bf(v.x);
    tile[tc*4+1][r] = f2bf(v.y);
    tile[tc*4+2][r] = f2bf(v.z);
    tile[tc*4+3][r] = f2bf(v.w);
  }
  __syncthreads();
  #pragma unroll
  for (int i = 0; i < 4; i++){
    int rr = tr + i * 16;   // dst row = src col
    ushort4 o;
    o.x = tile[rr][tc*4+0]; o.y = tile[rr][tc*4+1];
    o.z = tile[rr][tc*4+2]; o.w = tile[rr][tc*4+3];
    *(ushort4*)(d + (size_t)(c0 + rr) * R + r0 + tc * 4) = o;
  }
}

// ---------------- gating ----------------
// ctrl layout (ints): [0..7]=counts, [8..15]=padded offsets, [16..23]=cursors
// NOTE: no global atomics (R1: contended same-line atomics cost 200us).
__global__ __launch_bounds__(256)
void k_gate(const float* __restrict__ x, const float* __restrict__ wg,
            int* __restrict__ tidx, float* __restrict__ tgate){
  const int wave = threadIdx.x >> 6, lane = threadIdx.x & 63;
  const int t = blockIdx.x * 4 + wave;
  const float* xr = x + (size_t)t * DIM;
  double acc[8];
  #pragma unroll
  for (int e = 0; e < 8; e++) acc[e] = 0.0;
  for (int d = lane; d < DIM; d += 64){
    double xv = (double)xr[d];
    float4 a = *(const float4*)(wg + d * 8);
    float4 b = *(const float4*)(wg + d * 8 + 4);
    acc[0] += xv * (double)a.x; acc[1] += xv * (double)a.y;
    acc[2] += xv * (double)a.z; acc[3] += xv * (double)a.w;
    acc[4] += xv * (double)b.x; acc[5] += xv * (double)b.y;
    acc[6] += xv * (double)b.z; acc[7] += xv * (double)b.w;
  }
  #pragma unroll
  for (int off = 32; off > 0; off >>= 1){
    #pragma unroll
    for (int e = 0; e < 8; e++)
      acc[e] += __shfl_down(acc[e], off);
  }
  if (lane == 0){
    int i0 = 0; double v0 = acc[0];
    #pragma unroll
    for (int e = 1; e < 8; e++) if (acc[e] > v0){ v0 = acc[e]; i0 = e; }
    int i1 = -1; double v1 = -1e300;
    #pragma unroll
    for (int e = 0; e < 8; e++) if (e != i0 && acc[e] > v1){ v1 = acc[e]; i1 = e; }
    double g0 = 1.0 / (1.0 + exp(v1 - v0));  // softmax over top-2, stable (v1<=v0)
    tidx[2*t]   = i0; tidx[2*t+1] = i1;
    tgate[2*t]  = (float)g0;
    tgate[2*t+1]= (float)(1.0 - g0);
  }
}

// single block: histogram -> counts, BM-padded offsets, cursors, and the tile map
// tmap[tile] = (expert, m0); unused tiles get m0 = 1<<30 so the GEMM early-exit fires.
__global__ __launch_bounds__(1024)
void k_count(const int* __restrict__ tidx, int* __restrict__ ctrl,
             int2* __restrict__ tmap){
  __shared__ int hist[16][8];   // per-wave sub-histograms to cut LDS contention
  const int tid = threadIdx.x;
  const int wave = tid >> 6;
  if (tid < 128) ((int*)hist)[tid] = 0;
  __syncthreads();
  #pragma unroll
  for (int i = 0; i < 8; i++){
    int t = i * 1024 + tid;
    int2 e = ((const int2*)tidx)[t];
    atomicAdd(&hist[wave][e.x], 1);
    atomicAdd(&hist[wave][e.y], 1);
  }
  __syncthreads();
  if (tid == 0){
    int o = 0, nt = 0;
    for (int e = 0; e < 8; e++){
      int c = 0;
      for (int w = 0; w < 16; w++) c += hist[w][e];
      ctrl[e] = c; ctrl[8 + e] = o; ctrl[16 + e] = o;
      int tiles = (c + BM - 1) / BM;
      for (int tk = 0; tk < tiles; tk++) tmap[nt++] = make_int2(e, tk * BM);
      o += tiles * BM;                      // padded segment
    }
    for (; nt < MAXTILES; nt++) tmap[nt] = make_int2(0, 1 << 30);
  }
}

// block-aggregated placement: LDS ranks + 8 global atomics per block (256 total)
// also records each token's two slot positions for the combine pass
__global__ __launch_bounds__(256)
void k_place(const int* __restrict__ tidx, int* __restrict__ ctrl,
             int* __restrict__ perm, int2* __restrict__ slotpos){
  __shared__ int cnt[8];
  __shared__ int base[8];
  const int tid = threadIdx.x;
  if (tid < 8) cnt[tid] = 0;
  __syncthreads();
  const int t = blockIdx.x * 256 + tid;
  const int e0 = tidx[2*t], e1 = tidx[2*t+1];
  const int r0 = atomicAdd(&cnt[e0], 1);
  const int r1 = atomicAdd(&cnt[e1], 1);
  __syncthreads();
  if (tid < 8) base[tid] = atomicAdd(&ctrl[16 + tid], cnt[tid]);
  __syncthreads();
  const int p0 = base[e0] + r0, p1 = base[e1] + r1;
  perm[p0] = t;
  perm[p1] = t;
  slotpos[t] = make_int2(p0, p1);
}

// ---------------- pass A: h = gelu(Xg @ W1[e] + b1[e]) ----------------
// A: gathered token rows (bf16 [tok][D]); B: w1t = W1[e]^T bf16 [H][D]; out: h bf16 [slot][H]
// grid: x = n-tile (FAST dim), y = tile-map. n-fast makes the 16 blocks sharing one
// gathered A-tile dispatch-adjacent -> A fetched once into L2/L3 (R6: m-fast refetched
// A per n-tile, FETCH_SIZE 107 MB vs ~25 MB ideal; R2's n-fast gemm1 was faster).
__global__ __launch_bounds__(256, 4)
void k_gemm1(const unsigned short* __restrict__ xb,
             const unsigned short* __restrict__ w1t,
             const float* __restrict__ b1,
             unsigned short* __restrict__ h,
             const int* __restrict__ perm,
             const int* __restrict__ ctrl,
             const int2* __restrict__ tmap){
  const int2 tm = tmap[blockIdx.y];
  const int e = tm.x;
  const int m0 = tm.y;
  const int count = ctrl[e];
  if (m0 >= count) return;
  const int hoff = ctrl[8 + e];
  const int n0 = blockIdx.x * BN;

  // As/Bs staging (16K+16K ushorts) + 2K extra so the 4x(64x72) store-bounce fits
  __shared__ unsigned short smem[BM*BK + BN*BK + 2048];
  unsigned short* As = smem;
  unsigned short* Bs = smem + BM*BK;

  const int tid  = threadIdx.x;
  const int wave = tid >> 6;
  const int lane = tid & 63;
  const int rl   = wave * 32 + (lane >> 3);        // staging row (+8 per issue)
  const int swz  = (lane & 7) ^ ((lane >> 3) & 7); // xor-swizzled 16B chunk index

  const unsigned short* agp[4];
  const unsigned short* bgp[4];
  const unsigned short* w1e = w1t + (size_t)e * HID * DIM;
  #pragma unroll
  for (int i = 0; i < 4; i++){
    // padding slots: perm pre-zeroed -> token 0, valid address; store-masked below
    int srow = perm[hoff + m0 + rl + i * 8];
    agp[i] = xb + (size_t)srow * DIM + swz * 8;
    bgp[i] = w1e + (size_t)(n0 + rl + i * 8) * DIM + swz * 8;
  }
  unsigned short* asw = As + (wave * 32) * BK + lane * 8;
  unsigned short* bsw = Bs + (wave * 32) * BK + lane * 8;

  const int mh = (wave & 1) * 64;
  const int nh = (wave >> 1) * 64;
  const int fr = lane & 15;
  const int fq = lane >> 4;

  floatx4 acc[4][4];
  floatx4 zero = {0.f, 0.f, 0.f, 0.f};
  #pragma unroll
  for (int i = 0; i < 4; i++)
    #pragma unroll
    for (int j = 0; j < 4; j++) acc[i][j] = zero;

  for (int kt = 0; kt < DIM / BK; ++kt){
    #pragma unroll
    for (int i = 0; i < 4; i++){
      async_load16(agp[i] + kt * BK, asw + i * 8 * BK);
      async_load16(bgp[i] + kt * BK, bsw + i * 8 * BK);
    }
    __syncthreads();
    #pragma unroll
    for (int ks = 0; ks < 2; ks++){
      bf16x8 af[4], bfv[4];
      int kc = ks * 4 + fq;
      #pragma unroll
      for (int i = 0; i < 4; i++){
        int row = mh + i * 16 + fr;
        af[i] = *(const bf16x8*)(As + row * BK + ((kc ^ (row & 7)) << 3));
      }
      #pragma unroll
      for (int j = 0; j < 4; j++){
        int row = nh + j * 16 + fr;
        bfv[j] = *(const bf16x8*)(Bs + row * BK + ((kc ^ (row & 7)) << 3));
      }
      #pragma unroll
      for (int i = 0; i < 4; i++)
        #pragma unroll
        for (int j = 0; j < 4; j++)
          acc[i][j] = __builtin_amdgcn_mfma_f32_16x16x32_bf16(af[i], bfv[j], acc[i][j], 0, 0, 0);
    }
    __syncthreads();
  }

  // epilogue: bias + fast-exact gelu -> bf16, bounce through LDS for 16B stores
  unsigned short* wr = smem + wave * 4608;  // 64 rows x 72 (pad breaks bank conflicts)
  const int cm = fq * 4;
  const float* b1e = b1 + e * HID;
  #pragma unroll
  for (int i = 0; i < 4; i++){
    #pragma unroll
    for (int j = 0; j < 4; j++){
      float bias = b1e[n0 + nh + j * 16 + fr];
      #pragma unroll
      for (int r = 0; r < 4; r++){
        float v = acc[i][j][r] + bias;
        wr[(i * 16 + cm + r) * 72 + j * 16 + fr] = f2bf(gelu_fast(v));
      }
    }
  }
  __syncthreads();
  #pragma unroll
  for (int it = 0; it < 8; ++it){
    int row = it * 8 + (lane >> 3);
    int mrow = m0 + mh + row;
    if (mrow < count){
      uint4 vv = *(const uint4*)(wr + row * 72 + (lane & 7) * 8);
      *(uint4*)(h + (size_t)(hoff + mrow) * HID + n0 + nh + (lane & 7) * 8) = vv;
    }
  }
}

// ---------------- pass B: slots[slot] = h[slot] @ W2[e]  (bf16 out; no bias/gate) ----------------
// plain stores (NO atomics — R3: cross-XCD atomic RMW doubled duration).
// slots is bf16 so it fits entirely inside the dead xb+w1t region (17.8 < 25.2 MB):
// R4/R5's fp32 slots (33.6/35.7 MB) overflowed into w2t -> write-during-read race -> NaN (R5).
// grid: x = n-tile (fast) for h-row reuse, y = tile-map.
__global__ __launch_bounds__(256, 4)
void k_gemm2(const unsigned short* __restrict__ h,
             const unsigned short* __restrict__ w2t,
             unsigned short* __restrict__ slots,
             const int* __restrict__ ctrl,
             const int2* __restrict__ tmap){
  const int2 tm = tmap[blockIdx.y];
  const int e = tm.x;
  const int m0 = tm.y;
  const int count = ctrl[e];
  if (m0 >= count) return;
  const int hoff = ctrl[8 + e];
  const int n0 = blockIdx.x * BN2;

  __shared__ unsigned short smem[BM*BK + BN2*BK];   // 24 KB
  unsigned short* As = smem;
  unsigned short* Bs = smem + BM*BK;

  const int tid  = threadIdx.x;
  const int wave = tid >> 6;
  const int lane = tid & 63;
  const int rl   = wave * 32 + (lane >> 3);        // A staging rows (4 issues x +8)
  const int rlb  = wave * 16 + (lane >> 3);        // B staging rows (2 issues x +8)
  const int swz  = (lane & 7) ^ ((lane >> 3) & 7);

  const unsigned short* agp[4];
  const unsigned short* bgp[2];
  const unsigned short* w2e = w2t + (size_t)e * DIM * HID;
  #pragma unroll
  for (int i = 0; i < 4; i++){
    // padding rows of h hold poison bytes (finite bf16) — masked at store
    agp[i] = h + (size_t)(hoff + m0 + rl + i * 8) * HID + swz * 8;
  }
  #pragma unroll
  for (int i = 0; i < 2; i++){
    bgp[i] = w2e + (size_t)(n0 + rlb + i * 8) * HID + swz * 8;
  }
  unsigned short* asw = As + (wave * 32) * BK + lane * 8;
  unsigned short* bsw = Bs + (wave * 16) * BK + lane * 8;

  const int mh  = (wave & 1) * 64;
  const int nh2 = (wave >> 1) * 32;
  const int fr = lane & 15;
  const int fq = lane >> 4;

  floatx4 acc[4][2];
  floatx4 zero = {0.f, 0.f, 0.f, 0.f};
  #pragma unroll
  for (int i = 0; i < 4; i++)
    #pragma unroll
    for (int j = 0; j < 2; j++) acc[i][j] = zero;

  for (int kt = 0; kt < HID / BK; ++kt){
    #pragma unroll
    for (int i = 0; i < 4; i++)
      async_load16(agp[i] + kt * BK, asw + i * 8 * BK);
    #pragma unroll
    for (int i = 0; i < 2; i++)
      async_load16(bgp[i] + kt * BK, bsw + i * 8 * BK);
    __syncthreads();
    #pragma unroll
    for (int ks = 0; ks < 2; ks++){
      bf16x8 af[4], bfv[2];
      int kc = ks * 4 + fq;
      #pragma unroll
      for (int i = 0; i < 4; i++){
        int row = mh + i * 16 + fr;
        af[i] = *(const bf16x8*)(As + row * BK + ((kc ^ (row & 7)) << 3));
      }
      #pragma unroll
      for (int j = 0; j < 2; j++){
        int row = nh2 + j * 16 + fr;
        bfv[j] = *(const bf16x8*)(Bs + row * BK + ((kc ^ (row & 7)) << 3));
      }
      #pragma unroll
      for (int i = 0; i < 4; i++)
        #pragma unroll
        for (int j = 0; j < 2; j++)
          acc[i][j] = __builtin_amdgcn_mfma_f32_16x16x32_bf16(af[i], bfv[j], acc[i][j], 0, 0, 0);
    }
    __syncthreads();
  }

  const int cm = fq * 4;
  #pragma unroll
  for (int i = 0; i < 4; i++){
    #pragma unroll
    for (int r = 0; r < 4; r++){
      int mrow = m0 + mh + i * 16 + cm + r;
      if (mrow < count){
        unsigned short* sr = slots + (size_t)(hoff + mrow) * DIM + n0 + nh2 + fr;
        sr[0]  = f2bf(acc[i][0][r]);
        sr[16] = f2bf(acc[i][1][r]);
      }
    }
  }
}

// ---------------- combine: y[t] = g0*(slot[p0]+b2[e0]) + g1*(slot[p1]+b2[e1]) ----------------
__global__ __launch_bounds__(256)
void k_combine(const unsigned short* __restrict__ slots, const int2* __restrict__ slotpos,
               const int* __restrict__ tidx, const float* __restrict__ tgate,
               const float* __restrict__ b2, float* __restrict__ y){
  const int idx = blockIdx.x * 256 + threadIdx.x;
  const int t  = idx >> 7;            // 128 threads per token row
  const int c4 = (idx & 127) * 4;
  int2 sp = slotpos[t];
  ushort4 u0 = *(const ushort4*)(slots + (size_t)sp.x * DIM + c4);
  ushort4 u1 = *(const ushort4*)(slots + (size_t)sp.y * DIM + c4);
  int   e0 = tidx[2*t],  e1 = tidx[2*t+1];
  float g0 = tgate[2*t], g1 = tgate[2*t+1];
  float4 bb0 = *(const float4*)(b2 + e0 * DIM + c4);
  float4 bb1 = *(const float4*)(b2 + e1 * DIM + c4);
  float4 r;
  r.x = g0 * (bf2f(u0.x) + bb0.x) + g1 * (bf2f(u1.x) + bb1.x);
  r.y = g0 * (bf2f(u0.y) + bb0.y) + g1 * (bf2f(u1.y) + bb1.y);
  r.z = g0 * (bf2f(u0.z) + bb0.z) + g1 * (bf2f(u1.z) + bb1.z);
  r.w = g0 * (bf2f(u0.w) + bb0.w) + g1 * (bf2f(u1.w) + bb1.w);
  *(float4*)(y + (size_t)t * DIM + c4) = r;
}

// ---------------- launch ----------------
extern "C" void kernel_launch(void* const* d_in, const int* in_sizes, int n_in,
                              void* d_out, int out_size, void* d_ws, size_t ws_size,
                              hipStream_t stream){
  const float* x  = (const float*)d_in[0];
  const float* wg = (const float*)d_in[1];
  const float* W1 = (const float*)d_in[2];
  const float* b1 = (const float*)d_in[3];
  const float* W2 = (const float*)d_in[4];
  const float* b2 = (const float*)d_in[5];
  float* y = (float*)d_out;

  char* ws = (char*)d_ws;
  size_t off = 0;
  auto alloc = [&](size_t bytes) -> void* {
    void* p = ws + off;
    off = (off + bytes + 255) & ~(size_t)255;
    return p;
  };
  // region 0: xb (8.39 MB) + w1t (16.78 MB) = 25.17 MB, dead after k_gemm1.
  // slots (bf16, PAD_SLOTS*DIM*2 = 17.83 MB) aliases it — MUST stay <= 25.17 MB
  // (fp32 slots overflowed into w2t and raced: R5 NaN).
  unsigned short* xb   = (unsigned short*)alloc((size_t)B_TOK * DIM * 2);
  unsigned short* w1t  = (unsigned short*)alloc((size_t)NEXP * HID * DIM * 2);
  unsigned short* slots = (unsigned short*)ws;
  static_assert((size_t)PAD_SLOTS * DIM * 2 <= (size_t)B_TOK * DIM * 2 + (size_t)NEXP * HID * DIM * 2,
                "slots must fit in dead xb+w1t region");
  unsigned short* w2t  = (unsigned short*)alloc((size_t)NEXP * DIM * HID * 2);
  unsigned short* hbuf = (unsigned short*)alloc((size_t)PAD_SLOTS * HID * 2);
  int*   perm    = (int*)  alloc((size_t)PAD_SLOTS * 4);
  int2*  slotpos = (int2*) alloc((size_t)B_TOK * 8);
  int2*  tmap    = (int2*) alloc(MAXTILES * 8);
  int*   tidx  = (int*)  alloc(2 * B_TOK * 4);
  float* tgate = (float*)alloc(2 * B_TOK * 4);
  int*   ctrl  = (int*)  alloc(24 * 4);

  hipMemsetAsync(perm, 0, (size_t)PAD_SLOTS * 4, stream);  // padding slots -> token 0

  k_cvt_x<<<B_TOK * DIM / (256 * 4), 256, 0, stream>>>(x, xb);
  k_transpose_bf16<<<dim3(HID / 64, DIM / 64, NEXP), 256, 0, stream>>>(W1, w1t, DIM, HID);
  k_transpose_bf16<<<dim3(DIM / 64, HID / 64, NEXP), 256, 0, stream>>>(W2, w2t, HID, DIM);
  k_gate<<<B_TOK / 4, 256, 0, stream>>>(x, wg, tidx, tgate);
  k_count<<<1, 1024, 0, stream>>>(tidx, ctrl, tmap);
  k_place<<<B_TOK / 256, 256, 0, stream>>>(tidx, ctrl, perm, slotpos);
  // n-fast grids: blocks sharing an A-tile are dispatch-adjacent (L2/L3 A-reuse)
  k_gemm1<<<dim3(HID / BN, MAXTILES), 256, 0, stream>>>(xb, w1t, b1, hbuf, perm, ctrl, tmap);
  k_gemm2<<<dim3(DIM / BN2, MAXTILES), 256, 0, stream>>>(hbuf, w2t, slots, ctrl, tmap);
  k_combine<<<B_TOK * DIM / 4 / 256, 256, 0, stream>>>(slots, slotpos, tidx, tgate, b2, y);
}

// Round 8
// 290.402 us; speedup vs baseline: 1.1244x; 1.1244x over previous
//
#include <hip/hip_runtime.h>
#include <cstdint>

#define B_TOK 8192
#define DIM   512
#define NEXP  8
#define HID   2048

#define BM 128
#define BN 128
#define BK 64
#define BN2 64                           // gemm2 n-tile
#define MAXTILES (B_TOK * 2 / BM + NEXP) // 136 = 8 XCDs x 17 padded m-tiles
#define MPX 17                           // m-tiles per XCD
#define PAD_SLOTS (MAXTILES * BM)        // 17408

typedef float  floatx4 __attribute__((ext_vector_type(4)));
typedef __bf16 bf16x8  __attribute__((ext_vector_type(8)));

__device__ __forceinline__ unsigned short f2bf(float f){
  unsigned u = __float_as_uint(f);
  u += 0x7fffu + ((u >> 16) & 1u);
  return (unsigned short)(u >> 16);
}

__device__ __forceinline__ float bf2f(unsigned short u){
  return __uint_as_float((unsigned)u << 16);
}

// Abramowitz-Stegun 7.1.26 erf: max abs err 1.5e-7, straight-line (~15 VALU ops)
// vs libm erff's branchy ~30+. R4: erff epilogue made VALUBusy 39% > MfmaUtil 12%.
__device__ __forceinline__ float erf_fast(float x){
  float ax = fabsf(x);
  float t  = 1.0f / (1.0f + 0.3275911f * ax);
  float p  = t * (0.254829592f + t * (-0.284496736f + t * (1.421413741f +
             t * (-1.453152027f + t * 1.061405429f))));
  float r  = 1.0f - p * __expf(-ax * ax);
  return copysignf(r, x);
}

__device__ __forceinline__ float gelu_fast(float v){
  return 0.5f * v * (1.0f + erf_fast(v * 0.70710678118654752440f));
}

// global -> LDS async, 16B per lane. LDS dest is wave-uniform base + lane*16.
__device__ __forceinline__ void async_load16(const void* g, void* l){
  __builtin_amdgcn_global_load_lds(
      (__attribute__((address_space(1))) unsigned int*)const_cast<void*>(g),
      (__attribute__((address_space(3))) unsigned int*)l, 16, 0, 0);
}

// ---------------- prep kernels ----------------

__global__ void k_cvt_x(const float* __restrict__ x, unsigned short* __restrict__ xb){
  int i = blockIdx.x * blockDim.x + threadIdx.x;
  float4 v = ((const float4*)x)[i];
  ushort4 o;
  o.x = f2bf(v.x); o.y = f2bf(v.y); o.z = f2bf(v.z); o.w = f2bf(v.w);
  ((ushort4*)xb)[i] = o;
}

// transpose per-expert [R][C] fp32 -> [C][R] bf16
__global__ __launch_bounds__(256)
void k_transpose_bf16(const float* __restrict__ src, unsigned short* __restrict__ dst,
                      int R, int C){
  __shared__ unsigned short tile[64][65];
  const size_t eoff = (size_t)blockIdx.z * (size_t)R * (size_t)C;
  const float* s = src + eoff;
  unsigned short* d = dst + eoff;
  int r0 = blockIdx.y * 64, c0 = blockIdx.x * 64;
  int tr = threadIdx.x >> 4, tc = threadIdx.x & 15;
  #pragma unroll
  for (int i = 0; i < 4; i++){
    int r = tr + i * 16;
    float4 v = *(const float4*)(s + (size_t)(r0 + r) * C + c0 + tc * 4);
    tile[tc*4+0][r] = f2bf(v.x);
    tile[tc*4+1][r] = f2bf(v.y);
    tile[tc*4+2][r] = f2bf(v.z);
    tile[tc*4+3][r] = f2bf(v.w);
  }
  __syncthreads();
  #pragma unroll
  for (int i = 0; i < 4; i++){
    int rr = tr + i * 16;   // dst row = src col
    ushort4 o;
    o.x = tile[rr][tc*4+0]; o.y = tile[rr][tc*4+1];
    o.z = tile[rr][tc*4+2]; o.w = tile[rr][tc*4+3];
    *(ushort4*)(d + (size_t)(c0 + rr) * R + r0 + tc * 4) = o;
  }
}

// ---------------- gating ----------------
// ctrl layout (ints): [0..7]=counts, [8..15]=padded offsets, [16..23]=cursors
// NOTE: no global atomics (R1: contended same-line atomics cost 200us).
__global__ __launch_bounds__(256)
void k_gate(const float* __restrict__ x, const float* __restrict__ wg,
            int* __restrict__ tidx, float* __restrict__ tgate){
  const int wave = threadIdx.x >> 6, lane = threadIdx.x & 63;
  const int t = blockIdx.x * 4 + wave;
  const float* xr = x + (size_t)t * DIM;
  double acc[8];
  #pragma unroll
  for (int e = 0; e < 8; e++) acc[e] = 0.0;
  for (int d = lane; d < DIM; d += 64){
    double xv = (double)xr[d];
    float4 a = *(const float4*)(wg + d * 8);
    float4 b = *(const float4*)(wg + d * 8 + 4);
    acc[0] += xv * (double)a.x; acc[1] += xv * (double)a.y;
    acc[2] += xv * (double)a.z; acc[3] += xv * (double)a.w;
    acc[4] += xv * (double)b.x; acc[5] += xv * (double)b.y;
    acc[6] += xv * (double)b.z; acc[7] += xv * (double)b.w;
  }
  #pragma unroll
  for (int off = 32; off > 0; off >>= 1){
    #pragma unroll
    for (int e = 0; e < 8; e++)
      acc[e] += __shfl_down(acc[e], off);
  }
  if (lane == 0){
    int i0 = 0; double v0 = acc[0];
    #pragma unroll
    for (int e = 1; e < 8; e++) if (acc[e] > v0){ v0 = acc[e]; i0 = e; }
    int i1 = -1; double v1 = -1e300;
    #pragma unroll
    for (int e = 0; e < 8; e++) if (e != i0 && acc[e] > v1){ v1 = acc[e]; i1 = e; }
    double g0 = 1.0 / (1.0 + exp(v1 - v0));  // softmax over top-2, stable (v1<=v0)
    tidx[2*t]   = i0; tidx[2*t+1] = i1;
    tgate[2*t]  = (float)g0;
    tgate[2*t+1]= (float)(1.0 - g0);
  }
}

// single block: histogram -> counts, BM-padded offsets, cursors, and the tile map
// tmap[tile] = (expert, m0); unused tiles get m0 = 1<<30 so the GEMM early-exit fires.
__global__ __launch_bounds__(1024)
void k_count(const int* __restrict__ tidx, int* __restrict__ ctrl,
             int2* __restrict__ tmap){
  __shared__ int hist[16][8];   // per-wave sub-histograms to cut LDS contention
  const int tid = threadIdx.x;
  const int wave = tid >> 6;
  if (tid < 128) ((int*)hist)[tid] = 0;
  __syncthreads();
  #pragma unroll
  for (int i = 0; i < 8; i++){
    int t = i * 1024 + tid;
    int2 e = ((const int2*)tidx)[t];
    atomicAdd(&hist[wave][e.x], 1);
    atomicAdd(&hist[wave][e.y], 1);
  }
  __syncthreads();
  if (tid == 0){
    int o = 0, nt = 0;
    for (int e = 0; e < 8; e++){
      int c = 0;
      for (int w = 0; w < 16; w++) c += hist[w][e];
      ctrl[e] = c; ctrl[8 + e] = o; ctrl[16 + e] = o;
      int tiles = (c + BM - 1) / BM;
      for (int tk = 0; tk < tiles; tk++) tmap[nt++] = make_int2(e, tk * BM);
      o += tiles * BM;                      // padded segment
    }
    for (; nt < MAXTILES; nt++) tmap[nt] = make_int2(0, 1 << 30);
  }
}

// block-aggregated placement: LDS ranks + 8 global atomics per block (256 total)
// also records each token's two slot positions for the combine pass
__global__ __launch_bounds__(256)
void k_place(const int* __restrict__ tidx, int* __restrict__ ctrl,
             int* __restrict__ perm, int2* __restrict__ slotpos){
  __shared__ int cnt[8];
  __shared__ int base[8];
  const int tid = threadIdx.x;
  if (tid < 8) cnt[tid] = 0;
  __syncthreads();
  const int t = blockIdx.x * 256 + tid;
  const int e0 = tidx[2*t], e1 = tidx[2*t+1];
  const int r0 = atomicAdd(&cnt[e0], 1);
  const int r1 = atomicAdd(&cnt[e1], 1);
  __syncthreads();
  if (tid < 8) base[tid] = atomicAdd(&ctrl[16 + tid], cnt[tid]);
  __syncthreads();
  const int p0 = base[e0] + r0, p1 = base[e1] + r1;
  perm[p0] = t;
  perm[p1] = t;
  slotpos[t] = make_int2(p0, p1);
}

// XCD-aware swizzle (R7 lesson): HIP linear block id round-robins XCDs by %8.
// id = x + 8*(n + NT*mi): the NT blocks sharing an A-tile (same x,mi) have ids 8
// apart -> SAME XCD, temporally adjacent -> A-tile fetched once into one L2.
// m = x*17 + mi gives each XCD a contiguous 17-m-tile range (~2 experts) so the
// B (w*e, 2 MB/expert) working set fits the 4 MB per-XCD L2.

// ---------------- pass A: h = gelu(Xg @ W1[e] + b1[e]) ----------------
// A: gathered token rows (bf16 [tok][D]); B: w1t = W1[e]^T bf16 [H][D]; out: h bf16 [slot][H]
__global__ __launch_bounds__(256, 4)
void k_gemm1(const unsigned short* __restrict__ xb,
             const unsigned short* __restrict__ w1t,
             const float* __restrict__ b1,
             unsigned short* __restrict__ h,
             const int* __restrict__ perm,
             const int* __restrict__ ctrl,
             const int2* __restrict__ tmap){
  const int xcd = blockIdx.x & 7;
  const int g   = blockIdx.x >> 3;
  const int nti = g & 15;                 // 16 n-tiles
  const int mi  = g >> 4;                 // 0..16
  const int2 tm = tmap[xcd * MPX + mi];
  const int e = tm.x;
  const int m0 = tm.y;
  const int count = ctrl[e];
  if (m0 >= count) return;
  const int hoff = ctrl[8 + e];
  const int n0 = nti * BN;

  // As/Bs staging (16K+16K ushorts) + 2K extra so the 4x(64x72) store-bounce fits
  __shared__ unsigned short smem[BM*BK + BN*BK + 2048];
  unsigned short* As = smem;
  unsigned short* Bs = smem + BM*BK;

  const int tid  = threadIdx.x;
  const int wave = tid >> 6;
  const int lane = tid & 63;
  const int rl   = wave * 32 + (lane >> 3);        // staging row (+8 per issue)
  const int swz  = (lane & 7) ^ ((lane >> 3) & 7); // xor-swizzled 16B chunk index

  const unsigned short* agp[4];
  const unsigned short* bgp[4];
  const unsigned short* w1e = w1t + (size_t)e * HID * DIM;
  #pragma unroll
  for (int i = 0; i < 4; i++){
    // padding slots: perm pre-zeroed -> token 0, valid address; store-masked below
    int srow = perm[hoff + m0 + rl + i * 8];
    agp[i] = xb + (size_t)srow * DIM + swz * 8;
    bgp[i] = w1e + (size_t)(n0 + rl + i * 8) * DIM + swz * 8;
  }
  unsigned short* asw = As + (wave * 32) * BK + lane * 8;
  unsigned short* bsw = Bs + (wave * 32) * BK + lane * 8;

  const int mh = (wave & 1) * 64;
  const int nh = (wave >> 1) * 64;
  const int fr = lane & 15;
  const int fq = lane >> 4;

  floatx4 acc[4][4];
  floatx4 zero = {0.f, 0.f, 0.f, 0.f};
  #pragma unroll
  for (int i = 0; i < 4; i++)
    #pragma unroll
    for (int j = 0; j < 4; j++) acc[i][j] = zero;

  for (int kt = 0; kt < DIM / BK; ++kt){
    #pragma unroll
    for (int i = 0; i < 4; i++){
      async_load16(agp[i] + kt * BK, asw + i * 8 * BK);
      async_load16(bgp[i] + kt * BK, bsw + i * 8 * BK);
    }
    __syncthreads();
    #pragma unroll
    for (int ks = 0; ks < 2; ks++){
      bf16x8 af[4], bfv[4];
      int kc = ks * 4 + fq;
      #pragma unroll
      for (int i = 0; i < 4; i++){
        int row = mh + i * 16 + fr;
        af[i] = *(const bf16x8*)(As + row * BK + ((kc ^ (row & 7)) << 3));
      }
      #pragma unroll
      for (int j = 0; j < 4; j++){
        int row = nh + j * 16 + fr;
        bfv[j] = *(const bf16x8*)(Bs + row * BK + ((kc ^ (row & 7)) << 3));
      }
      #pragma unroll
      for (int i = 0; i < 4; i++)
        #pragma unroll
        for (int j = 0; j < 4; j++)
          acc[i][j] = __builtin_amdgcn_mfma_f32_16x16x32_bf16(af[i], bfv[j], acc[i][j], 0, 0, 0);
    }
    __syncthreads();
  }

  // epilogue: bias + fast-exact gelu -> bf16, bounce through LDS for 16B stores
  unsigned short* wr = smem + wave * 4608;  // 64 rows x 72 (pad breaks bank conflicts)
  const int cm = fq * 4;
  const float* b1e = b1 + e * HID;
  #pragma unroll
  for (int i = 0; i < 4; i++){
    #pragma unroll
    for (int j = 0; j < 4; j++){
      float bias = b1e[n0 + nh + j * 16 + fr];
      #pragma unroll
      for (int r = 0; r < 4; r++){
        float v = acc[i][j][r] + bias;
        wr[(i * 16 + cm + r) * 72 + j * 16 + fr] = f2bf(gelu_fast(v));
      }
    }
  }
  __syncthreads();
  #pragma unroll
  for (int it = 0; it < 8; ++it){
    int row = it * 8 + (lane >> 3);
    int mrow = m0 + mh + row;
    if (mrow < count){
      uint4 vv = *(const uint4*)(wr + row * 72 + (lane & 7) * 8);
      *(uint4*)(h + (size_t)(hoff + mrow) * HID + n0 + nh + (lane & 7) * 8) = vv;
    }
  }
}

// ---------------- pass B: slots[slot] = h[slot] @ W2[e]  (bf16 out; no bias/gate) ----------------
// plain stores (NO atomics — R3: cross-XCD atomic RMW doubled duration).
// slots is bf16 so it fits entirely inside the dead xb+w1t region (17.8 < 25.2 MB):
// R4/R5's fp32 slots (33.6/35.7 MB) overflowed into w2t -> write-during-read race -> NaN (R5).
__global__ __launch_bounds__(256, 4)
void k_gemm2(const unsigned short* __restrict__ h,
             const unsigned short* __restrict__ w2t,
             unsigned short* __restrict__ slots,
             const int* __restrict__ ctrl,
             const int2* __restrict__ tmap){
  const int xcd = blockIdx.x & 7;
  const int g   = blockIdx.x >> 3;
  const int nti = g & 7;                  // 8 n-tiles
  const int mi  = g >> 3;                 // 0..16
  const int2 tm = tmap[xcd * MPX + mi];
  const int e = tm.x;
  const int m0 = tm.y;
  const int count = ctrl[e];
  if (m0 >= count) return;
  const int hoff = ctrl[8 + e];
  const int n0 = nti * BN2;

  __shared__ unsigned short smem[BM*BK + BN2*BK];   // 24 KB
  unsigned short* As = smem;
  unsigned short* Bs = smem + BM*BK;

  const int tid  = threadIdx.x;
  const int wave = tid >> 6;
  const int lane = tid & 63;
  const int rl   = wave * 32 + (lane >> 3);        // A staging rows (4 issues x +8)
  const int rlb  = wave * 16 + (lane >> 3);        // B staging rows (2 issues x +8)
  const int swz  = (lane & 7) ^ ((lane >> 3) & 7);

  const unsigned short* agp[4];
  const unsigned short* bgp[2];
  const unsigned short* w2e = w2t + (size_t)e * DIM * HID;
  #pragma unroll
  for (int i = 0; i < 4; i++){
    // padding rows of h hold poison bytes (finite bf16) — masked at store
    agp[i] = h + (size_t)(hoff + m0 + rl + i * 8) * HID + swz * 8;
  }
  #pragma unroll
  for (int i = 0; i < 2; i++){
    bgp[i] = w2e + (size_t)(n0 + rlb + i * 8) * HID + swz * 8;
  }
  unsigned short* asw = As + (wave * 32) * BK + lane * 8;
  unsigned short* bsw = Bs + (wave * 16) * BK + lane * 8;

  const int mh  = (wave & 1) * 64;
  const int nh2 = (wave >> 1) * 32;
  const int fr = lane & 15;
  const int fq = lane >> 4;

  floatx4 acc[4][2];
  floatx4 zero = {0.f, 0.f, 0.f, 0.f};
  #pragma unroll
  for (int i = 0; i < 4; i++)
    #pragma unroll
    for (int j = 0; j < 2; j++) acc[i][j] = zero;

  for (int kt = 0; kt < HID / BK; ++kt){
    #pragma unroll
    for (int i = 0; i < 4; i++)
      async_load16(agp[i] + kt * BK, asw + i * 8 * BK);
    #pragma unroll
    for (int i = 0; i < 2; i++)
      async_load16(bgp[i] + kt * BK, bsw + i * 8 * BK);
    __syncthreads();
    #pragma unroll
    for (int ks = 0; ks < 2; ks++){
      bf16x8 af[4], bfv[2];
      int kc = ks * 4 + fq;
      #pragma unroll
      for (int i = 0; i < 4; i++){
        int row = mh + i * 16 + fr;
        af[i] = *(const bf16x8*)(As + row * BK + ((kc ^ (row & 7)) << 3));
      }
      #pragma unroll
      for (int j = 0; j < 2; j++){
        int row = nh2 + j * 16 + fr;
        bfv[j] = *(const bf16x8*)(Bs + row * BK + ((kc ^ (row & 7)) << 3));
      }
      #pragma unroll
      for (int i = 0; i < 4; i++)
        #pragma unroll
        for (int j = 0; j < 2; j++)
          acc[i][j] = __builtin_amdgcn_mfma_f32_16x16x32_bf16(af[i], bfv[j], acc[i][j], 0, 0, 0);
    }
    __syncthreads();
  }

  const int cm = fq * 4;
  #pragma unroll
  for (int i = 0; i < 4; i++){
    #pragma unroll
    for (int r = 0; r < 4; r++){
      int mrow = m0 + mh + i * 16 + cm + r;
      if (mrow < count){
        unsigned short* sr = slots + (size_t)(hoff + mrow) * DIM + n0 + nh2 + fr;
        sr[0]  = f2bf(acc[i][0][r]);
        sr[16] = f2bf(acc[i][1][r]);
      }
    }
  }
}

// ---------------- combine: y[t] = g0*(slot[p0]+b2[e0]) + g1*(slot[p1]+b2[e1]) ----------------
__global__ __launch_bounds__(256)
void k_combine(const unsigned short* __restrict__ slots, const int2* __restrict__ slotpos,
               const int* __restrict__ tidx, const float* __restrict__ tgate,
               const float* __restrict__ b2, float* __restrict__ y){
  const int idx = blockIdx.x * 256 + threadIdx.x;
  const int t  = idx >> 7;            // 128 threads per token row
  const int c4 = (idx & 127) * 4;
  int2 sp = slotpos[t];
  ushort4 u0 = *(const ushort4*)(slots + (size_t)sp.x * DIM + c4);
  ushort4 u1 = *(const ushort4*)(slots + (size_t)sp.y * DIM + c4);
  int   e0 = tidx[2*t],  e1 = tidx[2*t+1];
  float g0 = tgate[2*t], g1 = tgate[2*t+1];
  float4 bb0 = *(const float4*)(b2 + e0 * DIM + c4);
  float4 bb1 = *(const float4*)(b2 + e1 * DIM + c4);
  float4 r;
  r.x = g0 * (bf2f(u0.x) + bb0.x) + g1 * (bf2f(u1.x) + bb1.x);
  r.y = g0 * (bf2f(u0.y) + bb0.y) + g1 * (bf2f(u1.y) + bb1.y);
  r.z = g0 * (bf2f(u0.z) + bb0.z) + g1 * (bf2f(u1.z) + bb1.z);
  r.w = g0 * (bf2f(u0.w) + bb0.w) + g1 * (bf2f(u1.w) + bb1.w);
  *(float4*)(y + (size_t)t * DIM + c4) = r;
}

// ---------------- launch ----------------
extern "C" void kernel_launch(void* const* d_in, const int* in_sizes, int n_in,
                              void* d_out, int out_size, void* d_ws, size_t ws_size,
                              hipStream_t stream){
  const float* x  = (const float*)d_in[0];
  const float* wg = (const float*)d_in[1];
  const float* W1 = (const float*)d_in[2];
  const float* b1 = (const float*)d_in[3];
  const float* W2 = (const float*)d_in[4];
  const float* b2 = (const float*)d_in[5];
  float* y = (float*)d_out;

  char* ws = (char*)d_ws;
  size_t off = 0;
  auto alloc = [&](size_t bytes) -> void* {
    void* p = ws + off;
    off = (off + bytes + 255) & ~(size_t)255;
    return p;
  };
  // region 0: xb (8.39 MB) + w1t (16.78 MB) = 25.17 MB, dead after k_gemm1.
  // slots (bf16, PAD_SLOTS*DIM*2 = 17.83 MB) aliases it — MUST stay <= 25.17 MB
  // (fp32 slots overflowed into w2t and raced: R5 NaN).
  unsigned short* xb   = (unsigned short*)alloc((size_t)B_TOK * DIM * 2);
  unsigned short* w1t  = (unsigned short*)alloc((size_t)NEXP * HID * DIM * 2);
  unsigned short* slots = (unsigned short*)ws;
  static_assert((size_t)PAD_SLOTS * DIM * 2 <= (size_t)B_TOK * DIM * 2 + (size_t)NEXP * HID * DIM * 2,
                "slots must fit in dead xb+w1t region");
  unsigned short* w2t  = (unsigned short*)alloc((size_t)NEXP * DIM * HID * 2);
  unsigned short* hbuf = (unsigned short*)alloc((size_t)PAD_SLOTS * HID * 2);
  int*   perm    = (int*)  alloc((size_t)PAD_SLOTS * 4);
  int2*  slotpos = (int2*) alloc((size_t)B_TOK * 8);
  int2*  tmap    = (int2*) alloc(MAXTILES * 8);
  int*   tidx  = (int*)  alloc(2 * B_TOK * 4);
  float* tgate = (float*)alloc(2 * B_TOK * 4);
  int*   ctrl  = (int*)  alloc(24 * 4);

  hipMemsetAsync(perm, 0, (size_t)PAD_SLOTS * 4, stream);  // padding slots -> token 0

  k_cvt_x<<<B_TOK * DIM / (256 * 4), 256, 0, stream>>>(x, xb);
  k_transpose_bf16<<<dim3(HID / 64, DIM / 64, NEXP), 256, 0, stream>>>(W1, w1t, DIM, HID);
  k_transpose_bf16<<<dim3(DIM / 64, HID / 64, NEXP), 256, 0, stream>>>(W2, w2t, HID, DIM);
  k_gate<<<B_TOK / 4, 256, 0, stream>>>(x, wg, tidx, tgate);
  k_count<<<1, 1024, 0, stream>>>(tidx, ctrl, tmap);
  k_place<<<B_TOK / 256, 256, 0, stream>>>(tidx, ctrl, perm, slotpos);
  // 1-D grids with explicit XCD swizzle (see comment above k_gemm1)
  k_gemm1<<<MAXTILES * (HID / BN), 256, 0, stream>>>(xb, w1t, b1, hbuf, perm, ctrl, tmap);
  k_gemm2<<<MAXTILES * (DIM / BN2), 256, 0, stream>>>(hbuf, w2t, slots, ctrl, tmap);
  k_combine<<<B_TOK * DIM / 4 / 256, 256, 0, stream>>>(slots, slotpos, tidx, tgate, b2, y);
}

// Round 9
// 281.785 us; speedup vs baseline: 1.1588x; 1.0306x over previous
//
#include <hip/hip_runtime.h>
#include <cstdint>

#define B_TOK 8192
#define DIM   512
#define NEXP  8
#define HID   2048

#define BM 128
#define BN 128
#define BK 64
#define BN2 64                           // gemm2 n-tile
#define MAXTILES (B_TOK * 2 / BM + NEXP) // 136 = 8 XCDs x 17 padded m-tiles
#define MPX 17                           // m-tiles per XCD
#define PAD_SLOTS (MAXTILES * BM)        // 17408

typedef float  floatx4 __attribute__((ext_vector_type(4)));
typedef __bf16 bf16x8  __attribute__((ext_vector_type(8)));

__device__ __forceinline__ unsigned short f2bf(float f){
  unsigned u = __float_as_uint(f);
  u += 0x7fffu + ((u >> 16) & 1u);
  return (unsigned short)(u >> 16);
}

__device__ __forceinline__ float bf2f(unsigned short u){
  return __uint_as_float((unsigned)u << 16);
}

// Abramowitz-Stegun 7.1.26 erf: max abs err 1.5e-7, straight-line (~15 VALU ops)
__device__ __forceinline__ float erf_fast(float x){
  float ax = fabsf(x);
  float t  = 1.0f / (1.0f + 0.3275911f * ax);
  float p  = t * (0.254829592f + t * (-0.284496736f + t * (1.421413741f +
             t * (-1.453152027f + t * 1.061405429f))));
  float r  = 1.0f - p * __expf(-ax * ax);
  return copysignf(r, x);
}

__device__ __forceinline__ float gelu_fast(float v){
  return 0.5f * v * (1.0f + erf_fast(v * 0.70710678118654752440f));
}

// global -> LDS async, 16B per lane. LDS dest is wave-uniform base + lane*16.
__device__ __forceinline__ void async_load16(const void* g, void* l){
  __builtin_amdgcn_global_load_lds(
      (__attribute__((address_space(1))) unsigned int*)const_cast<void*>(g),
      (__attribute__((address_space(3))) unsigned int*)l, 16, 0, 0);
}

// ---------------- prep kernels ----------------

// transpose per-expert [R][C] fp32 -> [C][R] bf16
__global__ __launch_bounds__(256)
void k_transpose_bf16(const float* __restrict__ src, unsigned short* __restrict__ dst,
                      int R, int C){
  __shared__ unsigned short tile[64][65];
  const size_t eoff = (size_t)blockIdx.z * (size_t)R * (size_t)C;
  const float* s = src + eoff;
  unsigned short* d = dst + eoff;
  int r0 = blockIdx.y * 64, c0 = blockIdx.x * 64;
  int tr = threadIdx.x >> 4, tc = threadIdx.x & 15;
  #pragma unroll
  for (int i = 0; i < 4; i++){
    int r = tr + i * 16;
    float4 v = *(const float4*)(s + (size_t)(r0 + r) * C + c0 + tc * 4);
    tile[tc*4+0][r] = f2bf(v.x);
    tile[tc*4+1][r] = f2bf(v.y);
    tile[tc*4+2][r] = f2bf(v.z);
    tile[tc*4+3][r] = f2bf(v.w);
  }
  __syncthreads();
  #pragma unroll
  for (int i = 0; i < 4; i++){
    int rr = tr + i * 16;   // dst row = src col
    ushort4 o;
    o.x = tile[rr][tc*4+0]; o.y = tile[rr][tc*4+1];
    o.z = tile[rr][tc*4+2]; o.w = tile[rr][tc*4+3];
    *(ushort4*)(d + (size_t)(c0 + rr) * R + r0 + tc * 4) = o;
  }
}

// ---------------- gating (+ fused x -> bf16 conversion) ----------------
// ctrl layout (ints): [0..7]=counts, [8..15]=padded offsets, [16..23]=cursors
// NOTE: no global atomics (R1: contended same-line atomics cost 200us).
__global__ __launch_bounds__(256)
void k_gate(const float* __restrict__ x, const float* __restrict__ wg,
            int* __restrict__ tidx, float* __restrict__ tgate,
            unsigned short* __restrict__ xb){
  const int wave = threadIdx.x >> 6, lane = threadIdx.x & 63;
  const int t = blockIdx.x * 4 + wave;
  const float* xr = x + (size_t)t * DIM;
  unsigned short* xbr = xb + (size_t)t * DIM;
  double acc[8];
  #pragma unroll
  for (int e = 0; e < 8; e++) acc[e] = 0.0;
  for (int d = lane; d < DIM; d += 64){
    float xv = xr[d];
    xbr[d] = f2bf(xv);                   // fused cvt (was a separate 17MB-read kernel)
    double xd = (double)xv;
    float4 a = *(const float4*)(wg + d * 8);
    float4 b = *(const float4*)(wg + d * 8 + 4);
    acc[0] += xd * (double)a.x; acc[1] += xd * (double)a.y;
    acc[2] += xd * (double)a.z; acc[3] += xd * (double)a.w;
    acc[4] += xd * (double)b.x; acc[5] += xd * (double)b.y;
    acc[6] += xd * (double)b.z; acc[7] += xd * (double)b.w;
  }
  #pragma unroll
  for (int off = 32; off > 0; off >>= 1){
    #pragma unroll
    for (int e = 0; e < 8; e++)
      acc[e] += __shfl_down(acc[e], off);
  }
  if (lane == 0){
    int i0 = 0; double v0 = acc[0];
    #pragma unroll
    for (int e = 1; e < 8; e++) if (acc[e] > v0){ v0 = acc[e]; i0 = e; }
    int i1 = -1; double v1 = -1e300;
    #pragma unroll
    for (int e = 0; e < 8; e++) if (e != i0 && acc[e] > v1){ v1 = acc[e]; i1 = e; }
    double g0 = 1.0 / (1.0 + exp(v1 - v0));  // softmax over top-2, stable (v1<=v0)
    tidx[2*t]   = i0; tidx[2*t+1] = i1;
    tgate[2*t]  = (float)g0;
    tgate[2*t+1]= (float)(1.0 - g0);
  }
}

// single block: histogram -> counts, BM-padded offsets, cursors, and the tile map
// tmap[tile] = (expert, m0); unused tiles get m0 = 1<<30 so the GEMM early-exit fires.
__global__ __launch_bounds__(1024)
void k_count(const int* __restrict__ tidx, int* __restrict__ ctrl,
             int2* __restrict__ tmap){
  __shared__ int hist[16][8];   // per-wave sub-histograms to cut LDS contention
  const int tid = threadIdx.x;
  const int wave = tid >> 6;
  if (tid < 128) ((int*)hist)[tid] = 0;
  __syncthreads();
  #pragma unroll
  for (int i = 0; i < 8; i++){
    int t = i * 1024 + tid;
    int2 e = ((const int2*)tidx)[t];
    atomicAdd(&hist[wave][e.x], 1);
    atomicAdd(&hist[wave][e.y], 1);
  }
  __syncthreads();
  if (tid == 0){
    int o = 0, nt = 0;
    for (int e = 0; e < 8; e++){
      int c = 0;
      for (int w = 0; w < 16; w++) c += hist[w][e];
      ctrl[e] = c; ctrl[8 + e] = o; ctrl[16 + e] = o;
      int tiles = (c + BM - 1) / BM;
      for (int tk = 0; tk < tiles; tk++) tmap[nt++] = make_int2(e, tk * BM);
      o += tiles * BM;                      // padded segment
    }
    for (; nt < MAXTILES; nt++) tmap[nt] = make_int2(0, 1 << 30);
  }
}

// block-aggregated placement: LDS ranks + 8 global atomics per block (256 total)
__global__ __launch_bounds__(256)
void k_place(const int* __restrict__ tidx, int* __restrict__ ctrl,
             int* __restrict__ perm, int2* __restrict__ slotpos){
  __shared__ int cnt[8];
  __shared__ int base[8];
  const int tid = threadIdx.x;
  if (tid < 8) cnt[tid] = 0;
  __syncthreads();
  const int t = blockIdx.x * 256 + tid;
  const int e0 = tidx[2*t], e1 = tidx[2*t+1];
  const int r0 = atomicAdd(&cnt[e0], 1);
  const int r1 = atomicAdd(&cnt[e1], 1);
  __syncthreads();
  if (tid < 8) base[tid] = atomicAdd(&ctrl[16 + tid], cnt[tid]);
  __syncthreads();
  const int p0 = base[e0] + r0, p1 = base[e1] + r1;
  perm[p0] = t;
  perm[p1] = t;
  slotpos[t] = make_int2(p0, p1);
}

// XCD-aware swizzle (R8 WIN): id = xcd + 8*(n + NT*mi) -> blocks sharing an A-tile
// sit 8 ids apart = SAME XCD, adjacent in time; each XCD owns 17 contiguous m-tiles
// (~2 experts) so its B working set fits the 4 MB per-XCD L2. R8: FETCH 107->37 MB.
//
// B-column permutation (R9): feed sub-MFMA j from Bs row (nh + 4*fr + j) so each
// thread's j-outputs land on contiguous columns nh+4*fr..+3 -> direct ushort4
// stores; the old LDS store-bounce (64 ds_write_b16 + barrier + 8 ds_read) is gone.
// Chunk-XOR bank distribution is identical (8 lanes/chunk either way).

// ---------------- pass A: h = gelu(Xg @ W1[e] + b1[e]) ----------------
__global__ __launch_bounds__(256, 4)
void k_gemm1(const unsigned short* __restrict__ xb,
             const unsigned short* __restrict__ w1t,
             const float* __restrict__ b1,
             unsigned short* __restrict__ h,
             const int* __restrict__ perm,
             const int* __restrict__ ctrl,
             const int2* __restrict__ tmap){
  const int xcd = blockIdx.x & 7;
  const int g   = blockIdx.x >> 3;
  const int nti = g & 15;                 // 16 n-tiles
  const int mi  = g >> 4;                 // 0..16
  const int2 tm = tmap[xcd * MPX + mi];
  const int e = tm.x;
  const int m0 = tm.y;
  const int count = ctrl[e];
  if (m0 >= count) return;
  const int hoff = ctrl[8 + e];
  const int n0 = nti * BN;

  __shared__ unsigned short smem[BM*BK + BN*BK];    // 32 KB
  unsigned short* As = smem;
  unsigned short* Bs = smem + BM*BK;

  const int tid  = threadIdx.x;
  const int wave = tid >> 6;
  const int lane = tid & 63;
  const int rl   = wave * 32 + (lane >> 3);        // staging row (+8 per issue)
  const int swz  = (lane & 7) ^ ((lane >> 3) & 7); // xor-swizzled 16B chunk index

  const unsigned short* agp[4];
  const unsigned short* bgp[4];
  const unsigned short* w1e = w1t + (size_t)e * HID * DIM;
  #pragma unroll
  for (int i = 0; i < 4; i++){
    // padding slots: perm pre-zeroed -> token 0, valid address; store-masked below
    int srow = perm[hoff + m0 + rl + i * 8];
    agp[i] = xb + (size_t)srow * DIM + swz * 8;
    bgp[i] = w1e + (size_t)(n0 + rl + i * 8) * DIM + swz * 8;
  }
  unsigned short* asw = As + (wave * 32) * BK + lane * 8;
  unsigned short* bsw = Bs + (wave * 32) * BK + lane * 8;

  const int mh = (wave & 1) * 64;
  const int nh = (wave >> 1) * 64;
  const int fr = lane & 15;
  const int fq = lane >> 4;

  floatx4 acc[4][4];
  floatx4 zero = {0.f, 0.f, 0.f, 0.f};
  #pragma unroll
  for (int i = 0; i < 4; i++)
    #pragma unroll
    for (int j = 0; j < 4; j++) acc[i][j] = zero;

  for (int kt = 0; kt < DIM / BK; ++kt){
    #pragma unroll
    for (int i = 0; i < 4; i++){
      async_load16(agp[i] + kt * BK, asw + i * 8 * BK);
      async_load16(bgp[i] + kt * BK, bsw + i * 8 * BK);
    }
    __syncthreads();
    #pragma unroll
    for (int ks = 0; ks < 2; ks++){
      bf16x8 af[4], bfv[4];
      int kc = ks * 4 + fq;
      #pragma unroll
      for (int i = 0; i < 4; i++){
        int row = mh + i * 16 + fr;
        af[i] = *(const bf16x8*)(As + row * BK + ((kc ^ (row & 7)) << 3));
      }
      #pragma unroll
      for (int j = 0; j < 4; j++){
        int row = nh + fr * 4 + j;        // permuted: thread's j-cols contiguous
        bfv[j] = *(const bf16x8*)(Bs + row * BK + ((kc ^ (row & 7)) << 3));
      }
      #pragma unroll
      for (int i = 0; i < 4; i++)
        #pragma unroll
        for (int j = 0; j < 4; j++)
          acc[i][j] = __builtin_amdgcn_mfma_f32_16x16x32_bf16(af[i], bfv[j], acc[i][j], 0, 0, 0);
    }
    __syncthreads();
  }

  // epilogue: bias + fast gelu -> bf16, DIRECT ushort4 stores (no LDS bounce)
  const int cm = fq * 4;
  const int cn = n0 + nh + fr * 4;        // 4 contiguous output cols per thread
  float4 bias = *(const float4*)(b1 + e * HID + cn);
  #pragma unroll
  for (int i = 0; i < 4; i++){
    #pragma unroll
    for (int r = 0; r < 4; r++){
      int mrow = m0 + mh + i * 16 + cm + r;
      if (mrow < count){
        ushort4 o;
        o.x = f2bf(gelu_fast(acc[i][0][r] + bias.x));
        o.y = f2bf(gelu_fast(acc[i][1][r] + bias.y));
        o.z = f2bf(gelu_fast(acc[i][2][r] + bias.z));
        o.w = f2bf(gelu_fast(acc[i][3][r] + bias.w));
        *(ushort4*)(h + (size_t)(hoff + mrow) * HID + cn) = o;
      }
    }
  }
}

// ---------------- pass B: slots[slot] = h[slot] @ W2[e]  (bf16 out; no bias/gate) ----------------
// plain stores (NO atomics — R3); slots bf16 aliases dead xb+w1t (R5 NaN lesson).
__global__ __launch_bounds__(256, 4)
void k_gemm2(const unsigned short* __restrict__ h,
             const unsigned short* __restrict__ w2t,
             unsigned short* __restrict__ slots,
             const int* __restrict__ ctrl,
             const int2* __restrict__ tmap){
  const int xcd = blockIdx.x & 7;
  const int g   = blockIdx.x >> 3;
  const int nti = g & 7;                  // 8 n-tiles
  const int mi  = g >> 3;                 // 0..16
  const int2 tm = tmap[xcd * MPX + mi];
  const int e = tm.x;
  const int m0 = tm.y;
  const int count = ctrl[e];
  if (m0 >= count) return;
  const int hoff = ctrl[8 + e];
  const int n0 = nti * BN2;

  __shared__ unsigned short smem[BM*BK + BN2*BK];   // 24 KB
  unsigned short* As = smem;
  unsigned short* Bs = smem + BM*BK;

  const int tid  = threadIdx.x;
  const int wave = tid >> 6;
  const int lane = tid & 63;
  const int rl   = wave * 32 + (lane >> 3);        // A staging rows (4 issues x +8)
  const int rlb  = wave * 16 + (lane >> 3);        // B staging rows (2 issues x +8)
  const int swz  = (lane & 7) ^ ((lane >> 3) & 7);

  const unsigned short* agp[4];
  const unsigned short* bgp[2];
  const unsigned short* w2e = w2t + (size_t)e * DIM * HID;
  #pragma unroll
  for (int i = 0; i < 4; i++){
    // padding rows of h hold stale bytes (finite bf16) — masked at store
    agp[i] = h + (size_t)(hoff + m0 + rl + i * 8) * HID + swz * 8;
  }
  #pragma unroll
  for (int i = 0; i < 2; i++){
    bgp[i] = w2e + (size_t)(n0 + rlb + i * 8) * HID + swz * 8;
  }
  unsigned short* asw = As + (wave * 32) * BK + lane * 8;
  unsigned short* bsw = Bs + (wave * 16) * BK + lane * 8;

  const int mh  = (wave & 1) * 64;
  const int nh2 = (wave >> 1) * 32;
  const int fr = lane & 15;
  const int fq = lane >> 4;

  floatx4 acc[4][2];
  floatx4 zero = {0.f, 0.f, 0.f, 0.f};
  #pragma unroll
  for (int i = 0; i < 4; i++)
    #pragma unroll
    for (int j = 0; j < 2; j++) acc[i][j] = zero;

  for (int kt = 0; kt < HID / BK; ++kt){
    #pragma unroll
    for (int i = 0; i < 4; i++)
      async_load16(agp[i] + kt * BK, asw + i * 8 * BK);
    #pragma unroll
    for (int i = 0; i < 2; i++)
      async_load16(bgp[i] + kt * BK, bsw + i * 8 * BK);
    __syncthreads();
    #pragma unroll
    for (int ks = 0; ks < 2; ks++){
      bf16x8 af[4], bfv[2];
      int kc = ks * 4 + fq;
      #pragma unroll
      for (int i = 0; i < 4; i++){
        int row = mh + i * 16 + fr;
        af[i] = *(const bf16x8*)(As + row * BK + ((kc ^ (row & 7)) << 3));
      }
      #pragma unroll
      for (int j = 0; j < 2; j++){
        int row = nh2 + fr * 2 + j;       // permuted: thread's j-cols contiguous
        bfv[j] = *(const bf16x8*)(Bs + row * BK + ((kc ^ (row & 7)) << 3));
      }
      #pragma unroll
      for (int i = 0; i < 4; i++)
        #pragma unroll
        for (int j = 0; j < 2; j++)
          acc[i][j] = __builtin_amdgcn_mfma_f32_16x16x32_bf16(af[i], bfv[j], acc[i][j], 0, 0, 0);
    }
    __syncthreads();
  }

  const int cm = fq * 4;
  const int cn = n0 + nh2 + fr * 2;       // 2 contiguous cols -> one dword store
  #pragma unroll
  for (int i = 0; i < 4; i++){
    #pragma unroll
    for (int r = 0; r < 4; r++){
      int mrow = m0 + mh + i * 16 + cm + r;
      if (mrow < count){
        unsigned pk = (unsigned)f2bf(acc[i][0][r]) | ((unsigned)f2bf(acc[i][1][r]) << 16);
        *(unsigned*)(slots + (size_t)(hoff + mrow) * DIM + cn) = pk;
      }
    }
  }
}

// ---------------- combine: y[t] = g0*(slot[p0]+b2[e0]) + g1*(slot[p1]+b2[e1]) ----------------
__global__ __launch_bounds__(256)
void k_combine(const unsigned short* __restrict__ slots, const int2* __restrict__ slotpos,
               const int* __restrict__ tidx, const float* __restrict__ tgate,
               const float* __restrict__ b2, float* __restrict__ y){
  const int idx = blockIdx.x * 256 + threadIdx.x;
  const int t  = idx >> 7;            // 128 threads per token row
  const int c4 = (idx & 127) * 4;
  int2 sp = slotpos[t];
  ushort4 u0 = *(const ushort4*)(slots + (size_t)sp.x * DIM + c4);
  ushort4 u1 = *(const ushort4*)(slots + (size_t)sp.y * DIM + c4);
  int   e0 = tidx[2*t],  e1 = tidx[2*t+1];
  float g0 = tgate[2*t], g1 = tgate[2*t+1];
  float4 bb0 = *(const float4*)(b2 + e0 * DIM + c4);
  float4 bb1 = *(const float4*)(b2 + e1 * DIM + c4);
  float4 r;
  r.x = g0 * (bf2f(u0.x) + bb0.x) + g1 * (bf2f(u1.x) + bb1.x);
  r.y = g0 * (bf2f(u0.y) + bb0.y) + g1 * (bf2f(u1.y) + bb1.y);
  r.z = g0 * (bf2f(u0.z) + bb0.z) + g1 * (bf2f(u1.z) + bb1.z);
  r.w = g0 * (bf2f(u0.w) + bb0.w) + g1 * (bf2f(u1.w) + bb1.w);
  *(float4*)(y + (size_t)t * DIM + c4) = r;
}

// ---------------- launch ----------------
extern "C" void kernel_launch(void* const* d_in, const int* in_sizes, int n_in,
                              void* d_out, int out_size, void* d_ws, size_t ws_size,
                              hipStream_t stream){
  const float* x  = (const float*)d_in[0];
  const float* wg = (const float*)d_in[1];
  const float* W1 = (const float*)d_in[2];
  const float* b1 = (const float*)d_in[3];
  const float* W2 = (const float*)d_in[4];
  const float* b2 = (const float*)d_in[5];
  float* y = (float*)d_out;

  char* ws = (char*)d_ws;
  size_t off = 0;
  auto alloc = [&](size_t bytes) -> void* {
    void* p = ws + off;
    off = (off + bytes + 255) & ~(size_t)255;
    return p;
  };
  // region 0: xb (8.39 MB) + w1t (16.78 MB) = 25.17 MB, dead after k_gemm1.
  // slots (bf16, PAD_SLOTS*DIM*2 = 17.83 MB) aliases it — MUST stay <= 25.17 MB
  // (fp32 slots overflowed into w2t and raced: R5 NaN).
  unsigned short* xb   = (unsigned short*)alloc((size_t)B_TOK * DIM * 2);
  unsigned short* w1t  = (unsigned short*)alloc((size_t)NEXP * HID * DIM * 2);
  unsigned short* slots = (unsigned short*)ws;
  static_assert((size_t)PAD_SLOTS * DIM * 2 <= (size_t)B_TOK * DIM * 2 + (size_t)NEXP * HID * DIM * 2,
                "slots must fit in dead xb+w1t region");
  unsigned short* w2t  = (unsigned short*)alloc((size_t)NEXP * DIM * HID * 2);
  unsigned short* hbuf = (unsigned short*)alloc((size_t)PAD_SLOTS * HID * 2);
  int*   perm    = (int*)  alloc((size_t)PAD_SLOTS * 4);
  int2*  slotpos = (int2*) alloc((size_t)B_TOK * 8);
  int2*  tmap    = (int2*) alloc(MAXTILES * 8);
  int*   tidx  = (int*)  alloc(2 * B_TOK * 4);
  float* tgate = (float*)alloc(2 * B_TOK * 4);
  int*   ctrl  = (int*)  alloc(24 * 4);

  hipMemsetAsync(perm, 0, (size_t)PAD_SLOTS * 4, stream);  // padding slots -> token 0

  k_transpose_bf16<<<dim3(HID / 64, DIM / 64, NEXP), 256, 0, stream>>>(W1, w1t, DIM, HID);
  k_transpose_bf16<<<dim3(DIM / 64, HID / 64, NEXP), 256, 0, stream>>>(W2, w2t, HID, DIM);
  k_gate<<<B_TOK / 4, 256, 0, stream>>>(x, wg, tidx, tgate, xb);
  k_count<<<1, 1024, 0, stream>>>(tidx, ctrl, tmap);
  k_place<<<B_TOK / 256, 256, 0, stream>>>(tidx, ctrl, perm, slotpos);
  // 1-D grids with explicit XCD swizzle (see comment above k_gemm1)
  k_gemm1<<<MAXTILES * (HID / BN), 256, 0, stream>>>(xb, w1t, b1, hbuf, perm, ctrl, tmap);
  k_gemm2<<<MAXTILES * (DIM / BN2), 256, 0, stream>>>(hbuf, w2t, slots, ctrl, tmap);
  k_combine<<<B_TOK * DIM / 4 / 256, 256, 0, stream>>>(slots, slotpos, tidx, tgate, b2, y);
}